// Round 4
// baseline (152.026 us; speedup 1.0000x reference)
//
#include <hip/hip_runtime.h>
#include <stdint.h>

// Problem constants (match reference)
constexpr int N = 64, C = 256, H = 64, W = 64, P = 1024;
constexpr int PLANE   = H * W;        // 4096 floats = 16 KB
constexpr int TILE_F  = 4 * PLANE;    // 4-channel tile = 16384 floats = 64 KB
constexpr int THREADS = 512;          // 8 waves

typedef float v4f __attribute__((ext_vector_type(4)));

// Persistent-ish design: grid = 256 blocks (1/CU at 128 KB LDS), each block
// owns a fixed 8-channel group (cp = b>>3) and walks 8 images (one per XCD,
// n = (b&7) + 8q). Per image: two 4-plane tiles (64 KB each), double-buffered:
//   stage tile k+1 via async global_load_lds WHILE computing tile k from LDS;
//   one vmcnt(0)-drain barrier per tile (T3-lite 2-phase).
// Round-3 bottleneck was zero stage/compute overlap (1 block/CU, 15% HBM).
//
// Thread t owns points {t, t+512} x 8 channels: weights computed once per
// point, 16 ds_read gathers per tile (random x per lane -> ~2-way bank
// aliasing, free), and the 8-channel result is one full 32 B store sector.

__device__ __forceinline__ void stage_tile(const float* __restrict__ src,
                                           float* __restrict__ dst, int t) {
    // 4096 float4 per tile; wave-uniform LDS base + lane*16 (linear dest,
    // required by global_load_lds), per-lane global src. 8 issues/thread.
    const int tb = t & ~63;
    #pragma unroll
    for (int i = 0; i < 8; ++i) {
        const int j  = (i << 9) + t;    // float4 index (per-lane)
        const int jb = (i << 9) + tb;   // wave-uniform float4 base
        __builtin_amdgcn_global_load_lds(
            (const __attribute__((address_space(1))) void*)(src + (j << 2)),
            (__attribute__((address_space(3))) void*)(dst + (jb << 2)),
            16, 0, 0);
    }
}

struct PointCtx { int i00, i01, i10, i11; float w00, w01, w10, w11; };

__device__ __forceinline__ PointCtx make_ctx(float y, float x) {
    PointCtx c;
    const float y0f = floorf(y), x0f = floorf(x);
    const float ly = y - y0f, lx = x - x0f;
    const float hy = 1.0f - ly, hx = 1.0f - lx;
    const int y0 = (int)y0f, x0 = (int)x0f, y1 = y0 + 1, x1 = x0 + 1;
    const bool vy0 = (unsigned)y0 < (unsigned)H, vy1 = (unsigned)y1 < (unsigned)H;
    const bool vx0 = (unsigned)x0 < (unsigned)W, vx1 = (unsigned)x1 < (unsigned)W;
    const int yc0 = min(max(y0, 0), H - 1), yc1 = min(max(y1, 0), H - 1);
    const int xc0 = min(max(x0, 0), W - 1), xc1 = min(max(x1, 0), W - 1);
    c.i00 = yc0 * W + xc0; c.i01 = yc0 * W + xc1;
    c.i10 = yc1 * W + xc0; c.i11 = yc1 * W + xc1;
    // fold zero-padding mask into the weight (clamped idx is always a valid
    // address; v*0 == (v*0)*w exactly, matches reference bit-for-bit)
    c.w00 = (vy0 && vx0) ? hy * hx : 0.0f;
    c.w01 = (vy0 && vx1) ? hy * lx : 0.0f;
    c.w10 = (vy1 && vx0) ? ly * hx : 0.0f;
    c.w11 = (vy1 && vx1) ? ly * lx : 0.0f;
    return c;
}

__device__ __forceinline__ v4f gather4(const float* __restrict__ buf,
                                       const PointCtx& c) {
    // 4 planes at +0/16/32/48 KB -> single addr reg + ds_read offset imm
    v4f r;
    r.x = buf[0*PLANE + c.i00] * c.w00 + buf[0*PLANE + c.i01] * c.w01
        + buf[0*PLANE + c.i10] * c.w10 + buf[0*PLANE + c.i11] * c.w11;
    r.y = buf[1*PLANE + c.i00] * c.w00 + buf[1*PLANE + c.i01] * c.w01
        + buf[1*PLANE + c.i10] * c.w10 + buf[1*PLANE + c.i11] * c.w11;
    r.z = buf[2*PLANE + c.i00] * c.w00 + buf[2*PLANE + c.i01] * c.w01
        + buf[2*PLANE + c.i10] * c.w10 + buf[2*PLANE + c.i11] * c.w11;
    r.w = buf[3*PLANE + c.i00] * c.w00 + buf[3*PLANE + c.i01] * c.w01
        + buf[3*PLANE + c.i10] * c.w10 + buf[3*PLANE + c.i11] * c.w11;
    return r;
}

__global__ __launch_bounds__(THREADS) void progressive_sample_kernel(
    const float* __restrict__ inp,     // [N,C,H,W]
    const float* __restrict__ point,   // [N,P,2] (y,x)
    const float* __restrict__ offset,  // [N,P,2]
    float* __restrict__ out)           // [N,P,C]
{
    extern __shared__ float lds[];
    float* buf0 = lds;                 // even tile (channels cp*8 + 0..3)
    float* buf1 = lds + TILE_F;        // odd tile  (channels cp*8 + 4..7)

    const int b  = blockIdx.x;
    const int x8 = b & 7;              // XCD id under b%8 dispatch
    const int cp = b >> 3;             // channel-pair group 0..31
    const int t  = threadIdx.x;
    const int chan0 = cp << 3;         // first of 8 channels

    // prologue: stage first even tile (image x8)
    stage_tile(inp + ((size_t)x8 * C + chan0) * PLANE, buf0, t);
    asm volatile("s_waitcnt vmcnt(0)" ::: "memory");
    __syncthreads();

    const int p0 = t, p1 = t + THREADS;

    for (int q = 0; q < 8; ++q) {
        const int n = x8 + (q << 3);
        const size_t npbase = (size_t)n << 10;

        // coords FIRST so their wait is vmcnt(8) with stage loads in flight
        const float2 ptA = ((const float2*)point )[npbase + p0];
        const float2 ofA = ((const float2*)offset)[npbase + p0];
        const float2 ptB = ((const float2*)point )[npbase + p1];
        const float2 ofB = ((const float2*)offset)[npbase + p1];

        const float* srcbase = inp + ((size_t)n * C + chan0) * PLANE;
        stage_tile(srcbase + 4 * PLANE, buf1, t);       // async: odd tile

        const PointCtx c0 = make_ctx(ptA.x + ofA.x, ptA.y + ofA.y);
        const PointCtx c1 = make_ctx(ptB.x + ofB.x, ptB.y + ofB.y);

        const v4f a0 = gather4(buf0, c0);               // channels 0..3
        const v4f a1 = gather4(buf0, c1);
        __syncthreads();               // drains buf1 stage, fences buf0 reuse

        if (q < 7)                                       // async: next even tile
            stage_tile(inp + ((size_t)(n + 8) * C + chan0) * PLANE, buf0, t);

        const v4f b0 = gather4(buf1, c0);               // channels 4..7
        const v4f b1 = gather4(buf1, c1);

        float* o0 = out + (npbase + p0) * C + chan0;
        float* o1 = out + (npbase + p1) * C + chan0;
        __builtin_nontemporal_store(a0, (v4f*)o0);      // full 32 B sector
        __builtin_nontemporal_store(b0, (v4f*)(o0 + 4));
        __builtin_nontemporal_store(a1, (v4f*)o1);
        __builtin_nontemporal_store(b1, (v4f*)(o1 + 4));
        __syncthreads();               // drains buf0 stage, fences buf1 reuse
    }
}

extern "C" void kernel_launch(void* const* d_in, const int* in_sizes, int n_in,
                              void* d_out, int out_size, void* d_ws, size_t ws_size,
                              hipStream_t stream) {
    const float* inp    = (const float*)d_in[0];
    const float* point  = (const float*)d_in[1];
    const float* offset = (const float*)d_in[2];
    float* out = (float*)d_out;

    const size_t shmem = 2 * TILE_F * sizeof(float);    // 131072 B
    hipFuncSetAttribute(reinterpret_cast<const void*>(progressive_sample_kernel),
                        hipFuncAttributeMaxDynamicSharedMemorySize, (int)shmem);
    progressive_sample_kernel<<<256, THREADS, shmem, stream>>>(
        inp, point, offset, out);
}

// Round 5
// 93.469 us; speedup vs baseline: 1.6265x; 1.6265x over previous
//
#include <hip/hip_runtime.h>

// Problem constants (match reference)
constexpr int N = 64, C = 256, H = 64, W = 64, P = 1024;
constexpr int PLANE     = H * W;       // 4096 floats = 16 KB
constexpr int PLANE_PAD = PLANE + 4;   // +4 floats: plane c starts at bank 4c ->
                                       // the 4 lanes sharing a point hit banks
                                       // {0,4,8,12}+idx. 16B alignment kept.
constexpr int CG = 8;                  // channels per block (two 4-plane phases)
constexpr int THREADS = 512;           // 8 waves

typedef float v4f __attribute__((ext_vector_type(4)));

// Round-4 lessons applied: no async double-buffer pipeline (raced, absmax
// 0.0156), no per-lane 32B store chunks (3x WRITE amplification). Instead:
//   - 2 blocks/CU (73.8 KB LDS each): while block A stages 64 KB from HBM,
//     co-resident block B computes -> stage/compute overlap via TLP, which
//     round 3 (1 block/CU, strict alternation, 15% HBM / 11% VALU) lacked.
//   - single plane buffer, two phases (channels 0-3 then 4-7), all
//     barrier-separated synchronous code -> bit-exact, race-free.
//   - results transposed through LDS so final stores are the round-3
//     measured-clean pattern: consecutive lanes -> consecutive channel
//     addresses, 32 B per point per instruction (WRITE_SIZE was exactly 64 MB).
__global__ __launch_bounds__(THREADS) void progressive_sample_kernel(
    const float* __restrict__ inp,     // [N,C,H,W]
    const float* __restrict__ point,   // [N,P,2] (y,x)
    const float* __restrict__ offset,  // [N,P,2]
    float* __restrict__ out)           // [N,P,C]
{
    extern __shared__ float lds[];
    float* planes  = lds;                    // [4][PLANE_PAD] = 16400 floats
    float* coords  = lds + 4 * PLANE_PAD;    // [P][2] = 2048 floats
    float* results = lds;                    // overlay (after planes are dead):
                                             // [P][8] = 8192 floats < 16400

    const int b  = blockIdx.x;
    const int n  = b >> 5;                   // 32 channel-groups per image
    const int cg = b & 31;
    const int t  = threadIdx.x;
    const int chan0 = cg << 3;

    // --- coords: pos = point + offset, 512 float4 covers 1024 (y,x) pairs ---
    {
        const float4 p4 = ((const float4*)point )[((size_t)n << 9) + t];
        const float4 o4 = ((const float4*)offset)[((size_t)n << 9) + t];
        float4 r;
        r.x = p4.x + o4.x; r.y = p4.y + o4.y;
        r.z = p4.z + o4.z; r.w = p4.w + o4.w;
        ((float4*)coords)[t] = r;
    }

    const float* srcA = inp + (size_t)(n * C + chan0) * PLANE;

    // --- stage planes 0..3 (64 KB, coalesced float4, padded dest) ---
    #pragma unroll
    for (int i = 0; i < 8; ++i) {
        const int j  = (i << 9) + t;         // float4 index 0..4095
        const int pl = j >> 10, wi = j & 1023;
        *(float4*)(planes + pl * PLANE_PAD + wi * 4) = ((const float4*)srcA)[j];
    }
    __syncthreads();

    const int c4 = t & 3;                    // channel within phase
    const int pl = t >> 2;                   // point lane 0..127
    const float* __restrict__ myplane = planes + c4 * PLANE_PAD;

    float accA[8], accB[8];

    #pragma unroll
    for (int k = 0; k < 8; ++k) {            // phase A: channels 0..3
        const int p = (k << 7) + pl;
        const float y = coords[2 * p], x = coords[2 * p + 1];
        const float y0f = floorf(y), x0f = floorf(x);
        const float ly = y - y0f, lx = x - x0f;
        const float hy = 1.0f - ly, hx = 1.0f - lx;
        const int y0 = (int)y0f, x0 = (int)x0f, y1 = y0 + 1, x1 = x0 + 1;
        const bool vy0 = (unsigned)y0 < (unsigned)H, vy1 = (unsigned)y1 < (unsigned)H;
        const bool vx0 = (unsigned)x0 < (unsigned)W, vx1 = (unsigned)x1 < (unsigned)W;
        const int yc0 = min(max(y0, 0), H - 1), yc1 = min(max(y1, 0), H - 1);
        const int xc0 = min(max(x0, 0), W - 1), xc1 = min(max(x1, 0), W - 1);
        const float v00 = (vy0 && vx0) ? myplane[yc0 * W + xc0] : 0.0f;
        const float v01 = (vy0 && vx1) ? myplane[yc0 * W + xc1] : 0.0f;
        const float v10 = (vy1 && vx0) ? myplane[yc1 * W + xc0] : 0.0f;
        const float v11 = (vy1 && vx1) ? myplane[yc1 * W + xc1] : 0.0f;
        accA[k] = v00 * (hy * hx) + v01 * (hy * lx)
                + v10 * (ly * hx) + v11 * (ly * lx);
    }
    __syncthreads();                         // planes 0..3 reads complete

    // --- stage planes 4..7 into the same buffer ---
    const float* srcB = srcA + 4 * PLANE;
    #pragma unroll
    for (int i = 0; i < 8; ++i) {
        const int j  = (i << 9) + t;
        const int pl2 = j >> 10, wi = j & 1023;
        *(float4*)(planes + pl2 * PLANE_PAD + wi * 4) = ((const float4*)srcB)[j];
    }
    __syncthreads();

    #pragma unroll
    for (int k = 0; k < 8; ++k) {            // phase B: channels 4..7
        const int p = (k << 7) + pl;
        const float y = coords[2 * p], x = coords[2 * p + 1];
        const float y0f = floorf(y), x0f = floorf(x);
        const float ly = y - y0f, lx = x - x0f;
        const float hy = 1.0f - ly, hx = 1.0f - lx;
        const int y0 = (int)y0f, x0 = (int)x0f, y1 = y0 + 1, x1 = x0 + 1;
        const bool vy0 = (unsigned)y0 < (unsigned)H, vy1 = (unsigned)y1 < (unsigned)H;
        const bool vx0 = (unsigned)x0 < (unsigned)W, vx1 = (unsigned)x1 < (unsigned)W;
        const int yc0 = min(max(y0, 0), H - 1), yc1 = min(max(y1, 0), H - 1);
        const int xc0 = min(max(x0, 0), W - 1), xc1 = min(max(x1, 0), W - 1);
        const float v00 = (vy0 && vx0) ? myplane[yc0 * W + xc0] : 0.0f;
        const float v01 = (vy0 && vx1) ? myplane[yc0 * W + xc1] : 0.0f;
        const float v10 = (vy1 && vx0) ? myplane[yc1 * W + xc0] : 0.0f;
        const float v11 = (vy1 && vx1) ? myplane[yc1 * W + xc1] : 0.0f;
        accB[k] = v00 * (hy * hx) + v01 * (hy * lx)
                + v10 * (ly * hx) + v11 * (ly * lx);
    }
    __syncthreads();                         // planes 4..7 reads complete

    // --- transpose through LDS: results[p][8ch] ---
    #pragma unroll
    for (int k = 0; k < 8; ++k) {
        const int p = (k << 7) + pl;
        results[p * 8 + c4]     = accA[k];
        results[p * 8 + c4 + 4] = accB[k];
    }
    __syncthreads();

    // --- coalesced readout: lane-contiguous, 32 B per point (round-3 clean
    //     pattern), float4 NT stores, 4 iters ---
    const size_t outbase = ((size_t)n << 10) * C + chan0;
    #pragma unroll
    for (int i = 0; i < 4; ++i) {
        const int g   = (i << 9) + t;        // float4 index 0..2047
        const int p   = g >> 1;
        const int ch0 = (g & 1) << 2;
        const v4f v = ((const v4f*)results)[g];
        __builtin_nontemporal_store(v, (v4f*)(out + outbase + (size_t)p * C + ch0));
    }
}

extern "C" void kernel_launch(void* const* d_in, const int* in_sizes, int n_in,
                              void* d_out, int out_size, void* d_ws, size_t ws_size,
                              hipStream_t stream) {
    const float* inp    = (const float*)d_in[0];
    const float* point  = (const float*)d_in[1];
    const float* offset = (const float*)d_in[2];
    float* out = (float*)d_out;

    const size_t shmem = (size_t)(4 * PLANE_PAD + 2 * P) * sizeof(float); // 73792 B
    hipFuncSetAttribute(reinterpret_cast<const void*>(progressive_sample_kernel),
                        hipFuncAttributeMaxDynamicSharedMemorySize, (int)shmem);
    progressive_sample_kernel<<<N * (C / CG), THREADS, shmem, stream>>>(
        inp, point, offset, out);
}

// Round 6
// 88.931 us; speedup vs baseline: 1.7095x; 1.0510x over previous
//
#include <hip/hip_runtime.h>

// Problem constants (match reference)
constexpr int N = 64, C = 256, H = 64, W = 64, P = 1024;
constexpr int PLANE   = H * W;    // 4096 floats = 16 KB
constexpr int GC      = 16;       // channels per block: 16ch x 4B = one full
                                  // 64B output line per point -> one thread
                                  // writes whole lines (no write amplification)
constexpr int THREADS = 256;      // 4 waves
constexpr int PPT     = 4;        // points per thread (1024/256)

typedef float v4f __attribute__((ext_vector_type(4)));

// T3/T4 pipeline (m218 lesson): plane-granular double buffer. Per k:
//   issue stage(k+1) -> s_waitcnt vmcnt(4) [stage(k) landed, stage(k+1) still
//   in flight] -> raw s_barrier -> compute plane k -> lgkmcnt(0) -> s_barrier.
// NEVER __syncthreads() in the loop: it drains vmcnt(0) and kills the overlap
// (round 4's failure). vmcnt ledger: exactly 4 global_load_lds per wave per
// stage; no other VMEM inside the loop.
__device__ __forceinline__ void stage_plane(const float* __restrict__ src,
                                            float* __restrict__ dst, int t) {
    const int tb = t & ~63;            // wave-uniform LDS base (linear dest)
    #pragma unroll
    for (int i = 0; i < 4; ++i) {
        const int j  = (i << 8) + t;   // per-lane float4 index 0..1023
        const int jb = (i << 8) + tb;
        __builtin_amdgcn_global_load_lds(
            (const __attribute__((address_space(1))) void*)(src + (j << 2)),
            (__attribute__((address_space(3))) void*)(dst + (jb << 2)),
            16, 0, 0);
    }
}

__global__ __launch_bounds__(THREADS) void progressive_sample_kernel(
    const float* __restrict__ inp,     // [N,C,H,W]
    const float* __restrict__ point,   // [N,P,2] (y,x)
    const float* __restrict__ offset,  // [N,P,2]
    float* __restrict__ out)           // [N,P,C]
{
    __shared__ __align__(16) float buf0[PLANE];   // 16 KB
    __shared__ __align__(16) float buf1[PLANE];   // 16 KB  -> 4 blocks/CU

    const int b = blockIdx.x;
    const int n = b >> 4;              // 16 channel-groups per image
    const int g = b & 15;
    const int t = threadIdx.x;
    const int chan0 = g * GC;

    const float* src = inp + ((size_t)n * C + chan0) * PLANE;

    // --- prologue: issue coord loads (8x float2), then stage plane 0 ---
    float2 pt_[PPT], of_[PPT];
    #pragma unroll
    for (int i = 0; i < PPT; ++i) {
        const int p = (i << 8) + t;
        pt_[i] = ((const float2*)point )[((size_t)n << 10) + p];
        of_[i] = ((const float2*)offset)[((size_t)n << 10) + p];
    }
    stage_plane(src, buf0, t);

    // ctx once per point: corner indices + zero-pad-folded weights.
    // (consuming coords here auto-waits their vmcnt while stage0 stays in flight)
    int   i00[PPT], i01[PPT], i10[PPT], i11[PPT];
    float w00[PPT], w01[PPT], w10[PPT], w11[PPT];
    #pragma unroll
    for (int i = 0; i < PPT; ++i) {
        const float y = pt_[i].x + of_[i].x;
        const float x = pt_[i].y + of_[i].y;
        const float y0f = floorf(y), x0f = floorf(x);
        const float ly = y - y0f, lx = x - x0f;
        const float hy = 1.0f - ly, hx = 1.0f - lx;
        const int y0 = (int)y0f, x0 = (int)x0f, y1 = y0 + 1, x1 = x0 + 1;
        const bool vy0 = (unsigned)y0 < (unsigned)H, vy1 = (unsigned)y1 < (unsigned)H;
        const bool vx0 = (unsigned)x0 < (unsigned)W, vx1 = (unsigned)x1 < (unsigned)W;
        const int yc0 = min(max(y0, 0), H - 1), yc1 = min(max(y1, 0), H - 1);
        const int xc0 = min(max(x0, 0), W - 1), xc1 = min(max(x1, 0), W - 1);
        i00[i] = yc0 * W + xc0; i01[i] = yc0 * W + xc1;
        i10[i] = yc1 * W + xc0; i11[i] = yc1 * W + xc1;
        w00[i] = (vy0 && vx0) ? hy * hx : 0.0f;
        w01[i] = (vy0 && vx1) ? hy * lx : 0.0f;
        w10[i] = (vy1 && vx0) ? ly * hx : 0.0f;
        w11[i] = (vy1 && vx1) ? ly * lx : 0.0f;
    }

    float acc[PPT][GC];                // fully unrolled -> registers

    #pragma unroll
    for (int k = 0; k < GC; ++k) {
        const float* bufk = (k & 1) ? buf1 : buf0;
        float*       bufn = (k & 1) ? buf0 : buf1;
        if (k < GC - 1) {
            stage_plane(src + (size_t)(k + 1) * PLANE, bufn, t);
            asm volatile("s_waitcnt vmcnt(4)" ::: "memory");   // stage(k) landed
        } else {
            asm volatile("s_waitcnt vmcnt(0)" ::: "memory");
        }
        __builtin_amdgcn_sched_barrier(0);
        __builtin_amdgcn_s_barrier();      // all waves' stage(k) visible

        #pragma unroll
        for (int i = 0; i < PPT; ++i) {
            acc[i][k] = bufk[i00[i]] * w00[i] + bufk[i01[i]] * w01[i]
                      + bufk[i10[i]] * w10[i] + bufk[i11[i]] * w11[i];
        }

        asm volatile("s_waitcnt lgkmcnt(0)" ::: "memory");     // reads done
        __builtin_amdgcn_sched_barrier(0);
        __builtin_amdgcn_s_barrier();      // safe to overwrite bufk next iter
    }

    // --- stores: one thread writes the full 64 B line of its point ---
    // (same-instruction lane coalescing not needed; 4 back-to-back 16 B stores
    //  complete the line -> L2 write-back emits full lines. Plain stores, not
    //  NT: NT streamed 16 B sectors uncombined in round 4.)
    #pragma unroll
    for (int i = 0; i < PPT; ++i) {
        float* o = out + (((size_t)n << 10) + ((i << 8) + t)) * C + chan0;
        #pragma unroll
        for (int q = 0; q < 4; ++q) {
            v4f v = { acc[i][4*q+0], acc[i][4*q+1], acc[i][4*q+2], acc[i][4*q+3] };
            *(v4f*)(o + 4 * q) = v;
        }
    }
}

extern "C" void kernel_launch(void* const* d_in, const int* in_sizes, int n_in,
                              void* d_out, int out_size, void* d_ws, size_t ws_size,
                              hipStream_t stream) {
    const float* inp    = (const float*)d_in[0];
    const float* point  = (const float*)d_in[1];
    const float* offset = (const float*)d_in[2];
    float* out = (float*)d_out;

    progressive_sample_kernel<<<N * (C / GC), THREADS, 0, stream>>>(
        inp, point, offset, out);
}

// Round 7
// 82.187 us; speedup vs baseline: 1.8498x; 1.0821x over previous
//
#include <hip/hip_runtime.h>

// Problem constants (match reference)
constexpr int N = 64, C = 256, H = 64, W = 64, P = 1024;
constexpr int PLANE   = H * W;    // 4096 floats = 16 KB
constexpr int GC      = 8;        // channel-planes per block
constexpr int THREADS = 256;      // 4 waves
constexpr int PPT     = 4;        // points per thread (1024/256)
constexpr int NBUF    = 3;        // triple buffer -> prefetch distance 2

typedef float v4f __attribute__((ext_vector_type(4)));

// Round-6 lesson: 1-iteration prefetch window (~300 cyc) < HBM latency
// (~900 cyc) and 2 barriers/plane -> every plane stalled on vmcnt. Fix:
// triple buffer, distance-2 prefetch, ONE barrier per plane:
//   iter k top: vmcnt(4) [stage(k) landed; stage(k+1) still in flight]
//               + lgkmcnt(0) was done at end of iter k-1
//               -> s_barrier -> issue stage(k+2) into buf[(k+2)%3]
//               -> compute plane k -> lgkmcnt(0).
// Overwrite safety: stage(k+2) targets buf[(k-1)%3]; all waves drained their
// plane-(k-1) ds_reads (lgkmcnt(0)) before the iter-k barrier. 48 KB LDS ->
// 3 blocks/CU co-resident (12 waves/CU) for TLP on top of the pipeline.
__device__ __forceinline__ void stage_plane(const float* __restrict__ src,
                                            float* __restrict__ dst, int t) {
    const int tb = t & ~63;            // wave-uniform LDS base (linear dest)
    #pragma unroll
    for (int i = 0; i < 4; ++i) {
        const int j  = (i << 8) + t;   // per-lane float4 index 0..1023
        const int jb = (i << 8) + tb;
        __builtin_amdgcn_global_load_lds(
            (const __attribute__((address_space(1))) void*)(src + (j << 2)),
            (__attribute__((address_space(3))) void*)(dst + (jb << 2)),
            16, 0, 0);
    }
}

__global__ __launch_bounds__(THREADS) void progressive_sample_kernel(
    const float* __restrict__ inp,     // [N,C,H,W]
    const float* __restrict__ point,   // [N,P,2] (y,x)
    const float* __restrict__ offset,  // [N,P,2]
    float* __restrict__ out)           // [N,P,C]
{
    __shared__ __align__(16) float buf[NBUF][PLANE];   // 48 KB

    const int b = blockIdx.x;
    const int n = b >> 5;              // 32 channel-groups per image
    const int g = b & 31;
    const int t = threadIdx.x;
    const int chan0 = g * GC;

    const float* src = inp + ((size_t)n * C + chan0) * PLANE;

    // --- prologue: coord loads first, then 2 plane-stages in flight ---
    float2 pt_[PPT], of_[PPT];
    #pragma unroll
    for (int i = 0; i < PPT; ++i) {
        const int p = (i << 8) + t;
        pt_[i] = ((const float2*)point )[((size_t)n << 10) + p];
        of_[i] = ((const float2*)offset)[((size_t)n << 10) + p];
    }
    stage_plane(src,          buf[0], t);
    stage_plane(src + PLANE,  buf[1], t);

    // ctx per point (consumes coords -> waits vmcnt(8); stages stay in flight)
    int   i00[PPT], i01[PPT], i10[PPT], i11[PPT];
    float w00[PPT], w01[PPT], w10[PPT], w11[PPT];
    #pragma unroll
    for (int i = 0; i < PPT; ++i) {
        const float y = pt_[i].x + of_[i].x;
        const float x = pt_[i].y + of_[i].y;
        const float y0f = floorf(y), x0f = floorf(x);
        const float ly = y - y0f, lx = x - x0f;
        const float hy = 1.0f - ly, hx = 1.0f - lx;
        const int y0 = (int)y0f, x0 = (int)x0f, y1 = y0 + 1, x1 = x0 + 1;
        const bool vy0 = (unsigned)y0 < (unsigned)H, vy1 = (unsigned)y1 < (unsigned)H;
        const bool vx0 = (unsigned)x0 < (unsigned)W, vx1 = (unsigned)x1 < (unsigned)W;
        const int yc0 = min(max(y0, 0), H - 1), yc1 = min(max(y1, 0), H - 1);
        const int xc0 = min(max(x0, 0), W - 1), xc1 = min(max(x1, 0), W - 1);
        i00[i] = yc0 * W + xc0; i01[i] = yc0 * W + xc1;
        i10[i] = yc1 * W + xc0; i11[i] = yc1 * W + xc1;
        w00[i] = (vy0 && vx0) ? hy * hx : 0.0f;
        w01[i] = (vy0 && vx1) ? hy * lx : 0.0f;
        w10[i] = (vy1 && vx0) ? ly * hx : 0.0f;
        w11[i] = (vy1 && vx1) ? ly * lx : 0.0f;
    }

    float acc[PPT][GC];

    #pragma unroll
    for (int k = 0; k < GC; ++k) {
        // stage(k) landed; stage(k+1) stays in flight
        if (k < GC - 1) {
            asm volatile("s_waitcnt vmcnt(4)" ::: "memory");
        } else {
            asm volatile("s_waitcnt vmcnt(0)" ::: "memory");
        }
        __builtin_amdgcn_sched_barrier(0);
        __builtin_amdgcn_s_barrier();      // all waves: stage(k) visible AND
                                           // all plane-(k-1) reads drained
        __builtin_amdgcn_sched_barrier(0);

        if (k + 2 < GC)                    // distance-2 prefetch
            stage_plane(src + (size_t)(k + 2) * PLANE, buf[(k + 2) % NBUF], t);

        const float* __restrict__ bk = buf[k % NBUF];
        #pragma unroll
        for (int i = 0; i < PPT; ++i) {
            acc[i][k] = bk[i00[i]] * w00[i] + bk[i01[i]] * w01[i]
                      + bk[i10[i]] * w10[i] + bk[i11[i]] * w11[i];
        }

        asm volatile("s_waitcnt lgkmcnt(0)" ::: "memory");   // my reads done
        __builtin_amdgcn_sched_barrier(0);
    }

    // --- stores: thread owns 32 B (8 ch) per point, 2x16 B back-to-back;
    //     plain cached stores (L2 merges; NT streamed 16 B sectors in rd 4) ---
    #pragma unroll
    for (int i = 0; i < PPT; ++i) {
        float* o = out + (((size_t)n << 10) + ((i << 8) + t)) * C + chan0;
        v4f v0 = { acc[i][0], acc[i][1], acc[i][2], acc[i][3] };
        v4f v1 = { acc[i][4], acc[i][5], acc[i][6], acc[i][7] };
        *(v4f*)o       = v0;
        *(v4f*)(o + 4) = v1;
    }
}

extern "C" void kernel_launch(void* const* d_in, const int* in_sizes, int n_in,
                              void* d_out, int out_size, void* d_ws, size_t ws_size,
                              hipStream_t stream) {
    const float* inp    = (const float*)d_in[0];
    const float* point  = (const float*)d_in[1];
    const float* offset = (const float*)d_in[2];
    float* out = (float*)d_out;

    progressive_sample_kernel<<<N * (C / GC), THREADS, 0, stream>>>(
        inp, point, offset, out);
}